// Round 1
// baseline (783.462 us; speedup 1.0000x reference)
//
#include <hip/hip_runtime.h>
#include <math.h>

#define NN 10000
#define NE 320000
#define DD 64
#define TILE 128
#define NTILE 79            // ceil(10000/128)
#define NPAD (NTILE * TILE) // 10112

// workspace layout (float offsets, all 16B-aligned)
#define OFF_DEG   0          // [10000]
#define OFF_DINV  10000      // [10000]
#define OFF_H     20000      // [640000]
#define OFF_AGG   660000     // [640000]
#define OFF_ZR    1300000    // [NPAD*64 = 647168]
// total = 1,947,168 floats = 7,788,672 bytes

// ---------------------------------------------------------------------------
// init: deg = 1 (self loop), agg = 0, zr = 0 (pad rows must stay 0)
__global__ void init_kernel(float* __restrict__ deg, float* __restrict__ agg,
                            float* __restrict__ zr) {
    int tid = blockIdx.x * 256 + threadIdx.x;
    if (tid < NN) deg[tid] = 1.0f;
    if (tid < NN * DD) agg[tid] = 0.0f;
    if (tid < NPAD * DD) zr[tid] = 0.0f;
}

// ---------------------------------------------------------------------------
// in-degree over destination nodes (col = edge_index[1])
__global__ void deg_kernel(const int* __restrict__ ei, float* __restrict__ deg) {
    int e = blockIdx.x * 256 + threadIdx.x;
    if (e < NE) atomicAdd(&deg[ei[NE + e]], 1.0f);
}

__global__ void dinv_kernel(const float* __restrict__ deg, float* __restrict__ dinv) {
    int i = blockIdx.x * 256 + threadIdx.x;
    if (i < NN) dinv[i] = rsqrtf(deg[i]);   // deg >= 1 always (self loop)
}

// ---------------------------------------------------------------------------
// h = z @ W   (4 rows per block, W staged in LDS)
__global__ __launch_bounds__(256) void h_kernel(const float* __restrict__ z,
                                                const float* __restrict__ W,
                                                float* __restrict__ h) {
    __shared__ float Ws[64 * 64];
    __shared__ float zs[4 * 64];
    const int tid = threadIdx.x;
    const int rbase = blockIdx.x * 4;
#pragma unroll
    for (int i = 0; i < 16; i++) Ws[i * 256 + tid] = W[i * 256 + tid];
    zs[tid] = z[rbase * DD + tid];
    __syncthreads();
    const int r = tid >> 6, d = tid & 63;
    float acc = 0.0f;
#pragma unroll
    for (int k = 0; k < 64; k++) acc = fmaf(zs[r * 64 + k], Ws[k * 64 + d], acc);
    h[(rbase + r) * DD + d] = acc;
}

// ---------------------------------------------------------------------------
// scatter: agg[col] += h[row] * dinv[row]*dinv[col]; 16 threads per edge
__global__ void scatter_kernel(const int* __restrict__ ei,
                               const float* __restrict__ dinv,
                               const float* __restrict__ h,
                               float* __restrict__ agg) {
    int tid = blockIdx.x * 256 + threadIdx.x;
    int e = tid >> 4, q = tid & 15;
    if (e >= NE) return;
    int r = ei[e];
    int c = ei[NE + e];
    float nrm = dinv[r] * dinv[c];
    const float4 hv = *(const float4*)&h[r * DD + q * 4];
    float* ap = &agg[c * DD + q * 4];
    atomicAdd(ap + 0, hv.x * nrm);
    atomicAdd(ap + 1, hv.y * nrm);
    atomicAdd(ap + 2, hv.z * nrm);
    atomicAdd(ap + 3, hv.w * nrm);
}

// ---------------------------------------------------------------------------
// zr = relu(agg + h*dinv^2 (self loop) + b)
__global__ void relu_kernel(const float* __restrict__ agg,
                            const float* __restrict__ h,
                            const float* __restrict__ dinv,
                            const float* __restrict__ b,
                            float* __restrict__ zr) {
    int tid = blockIdx.x * 256 + threadIdx.x;
    if (tid >= NN * DD) return;
    int i = tid >> 6, d = tid & 63;
    float di = dinv[i];
    float v = agg[tid] + h[tid] * di * di + b[d];
    zr[tid] = v > 0.0f ? v : 0.0f;
}

// ---------------------------------------------------------------------------
// C = zr @ zr^T, 128x128 tile per block, 8x8 per thread, K=64 in 2 phases of 32
__global__ __launch_bounds__(256) void gemm_kernel(const float* __restrict__ zr,
                                                   float* __restrict__ C) {
    __shared__ float As[32][TILE + 4];  // k-major: As[k][r]
    __shared__ float Bs[32][TILE + 4];
    const int tid = threadIdx.x;
    const int tx = tid & 15, ty = tid >> 4;
    const int rbase = blockIdx.y * TILE;
    const int cbase = blockIdx.x * TILE;

    float acc[8][8];
#pragma unroll
    for (int i = 0; i < 8; i++)
#pragma unroll
        for (int j = 0; j < 8; j++) acc[i][j] = 0.0f;

    for (int kp = 0; kp < 2; kp++) {
        __syncthreads();
#pragma unroll
        for (int i = 0; i < 16; i++) {
            int lin = i * 256 + tid;          // 0..4095
            int r = lin >> 5, k = lin & 31;   // r in [0,128), k in [0,32)
            As[k][r] = zr[(rbase + r) * DD + kp * 32 + k];  // zr padded: safe
            Bs[k][r] = zr[(cbase + r) * DD + kp * 32 + k];
        }
        __syncthreads();
#pragma unroll 4
        for (int k = 0; k < 32; k++) {
            const float4 a0 = *(const float4*)&As[k][ty * 8];
            const float4 a1 = *(const float4*)&As[k][ty * 8 + 4];
            const float4 b0 = *(const float4*)&Bs[k][tx * 8];
            const float4 b1 = *(const float4*)&Bs[k][tx * 8 + 4];
            float av[8] = {a0.x, a0.y, a0.z, a0.w, a1.x, a1.y, a1.z, a1.w};
            float bv[8] = {b0.x, b0.y, b0.z, b0.w, b1.x, b1.y, b1.z, b1.w};
#pragma unroll
            for (int i = 0; i < 8; i++)
#pragma unroll
                for (int j = 0; j < 8; j++)
                    acc[i][j] = fmaf(av[i], bv[j], acc[i][j]);
        }
    }

#pragma unroll
    for (int i = 0; i < 8; i++) {
        int row = rbase + ty * 8 + i;
        int colb = cbase + tx * 8;
        if (row < NN && colb < NN) {  // colb mult of 8, NN mult of 8 -> full float4s
            float4 s0 = make_float4(acc[i][0], acc[i][1], acc[i][2], acc[i][3]);
            float4 s1 = make_float4(acc[i][4], acc[i][5], acc[i][6], acc[i][7]);
            float* cp = &C[(size_t)row * NN + colb];
            *(float4*)(cp) = s0;
            *(float4*)(cp + 4) = s1;
        }
    }
}

// ---------------------------------------------------------------------------
extern "C" void kernel_launch(void* const* d_in, const int* in_sizes, int n_in,
                              void* d_out, int out_size, void* d_ws, size_t ws_size,
                              hipStream_t stream) {
    const float* z = (const float*)d_in[0];
    const int* ei = (const int*)d_in[1];     // [2, E] int32: row=ei[0:E], col=ei[E:2E]
    const float* W = (const float*)d_in[2];
    const float* b = (const float*)d_in[3];
    float* C = (float*)d_out;

    float* ws = (float*)d_ws;
    float* deg = ws + OFF_DEG;
    float* dinv = ws + OFF_DINV;
    float* h = ws + OFF_H;
    float* agg = ws + OFF_AGG;
    float* zr = ws + OFF_ZR;

    init_kernel<<<(NPAD * DD + 255) / 256, 256, 0, stream>>>(deg, agg, zr);
    deg_kernel<<<(NE + 255) / 256, 256, 0, stream>>>(ei, deg);
    dinv_kernel<<<(NN + 255) / 256, 256, 0, stream>>>(deg, dinv);
    h_kernel<<<NN / 4, 256, 0, stream>>>(z, W, h);
    scatter_kernel<<<(NE * 16 + 255) / 256, 256, 0, stream>>>(ei, dinv, h, agg);
    relu_kernel<<<(NN * DD + 255) / 256, 256, 0, stream>>>(agg, h, dinv, b, zr);

    dim3 grid(NTILE, NTILE);
    gemm_kernel<<<grid, 256, 0, stream>>>(zr, C);
}

// Round 2
// 548.397 us; speedup vs baseline: 1.4286x; 1.4286x over previous
//
#include <hip/hip_runtime.h>
#include <math.h>

#define NN 10000
#define NE 320000
#define DD 64
#define TILE 128
#define NTILE 79            // ceil(10000/128)
#define NPAD (NTILE * TILE) // 10112
#define PADROWS (NPAD - NN) // 112

typedef __bf16 bf16x8 __attribute__((ext_vector_type(8)));
typedef float f32x4 __attribute__((ext_vector_type(4)));

// workspace layout (byte offsets, 16B-aligned)
// cnt    int[10016]        @ 0
// fill   int[10016]        @ 40064
// rowptr int[10016]        @ 80128
// srcrow int[320000]       @ 120192
// dinv   float[10016]      @ 1400192
// h      float[640000]     @ 1440256
// zr1    bf16[NPAD*64]     @ 4000256   (1294336 B)
// zr2    bf16[NPAD*64]     @ 5294592   -> end 6588928 B
#define OFF_CNT    0
#define OFF_FILL   40064
#define OFF_ROWPTR 80128
#define OFF_SRC    120192
#define OFF_DINV   1400192
#define OFF_H      1440256
#define OFF_ZR1    4000256
#define OFF_ZR2    5294592

// ---------------------------------------------------------------------------
// zero cnt, fill; zero pad rows of zr1/zr2 (rows NN..NPAD)
__global__ void init_kernel(int* __restrict__ cnt, int* __restrict__ fill,
                            unsigned short* __restrict__ zr1,
                            unsigned short* __restrict__ zr2) {
    int tid = blockIdx.x * 256 + threadIdx.x;
    if (tid < NN) { cnt[tid] = 0; fill[tid] = 0; }
    if (tid < PADROWS * DD) {
        zr1[NN * DD + tid] = 0;
        zr2[NN * DD + tid] = 0;
    }
}

// ---------------------------------------------------------------------------
__global__ void count_kernel(const int* __restrict__ ei, int* __restrict__ cnt) {
    int e = blockIdx.x * 256 + threadIdx.x;
    if (e < NE) atomicAdd(&cnt[ei[NE + e]], 1);
}

__global__ void dinv_kernel(const int* __restrict__ cnt, float* __restrict__ dinv) {
    int i = blockIdx.x * 256 + threadIdx.x;
    if (i < NN) dinv[i] = rsqrtf((float)cnt[i] + 1.0f);  // +1 self loop
}

// ---------------------------------------------------------------------------
// single-block exclusive scan of cnt[NN] -> rowptr[NN+1]
__global__ __launch_bounds__(256) void scan_kernel(const int* __restrict__ cnt,
                                                   int* __restrict__ rowptr) {
    __shared__ int partial[256];
    const int t = threadIdx.x;
    const int base = t * 40;  // 256*40 = 10240 >= NN
    int s = 0;
#pragma unroll 4
    for (int i = 0; i < 40; i++) {
        int idx = base + i;
        if (idx < NN) s += cnt[idx];
    }
    partial[t] = s;
    __syncthreads();
    for (int off = 1; off < 256; off <<= 1) {
        int v = (t >= off) ? partial[t - off] : 0;
        __syncthreads();
        partial[t] += v;
        __syncthreads();
    }
    int run = (t == 0) ? 0 : partial[t - 1];
    for (int i = 0; i < 40; i++) {
        int idx = base + i;
        if (idx < NN) { rowptr[idx] = run; run += cnt[idx]; }
    }
    if (t == 255) rowptr[NN] = partial[255];
}

// ---------------------------------------------------------------------------
__global__ void fill_kernel(const int* __restrict__ ei,
                            const int* __restrict__ rowptr,
                            int* __restrict__ fill, int* __restrict__ srcrow) {
    int e = blockIdx.x * 256 + threadIdx.x;
    if (e >= NE) return;
    int c = ei[NE + e];
    int pos = rowptr[c] + atomicAdd(&fill[c], 1);
    srcrow[pos] = ei[e];
}

// ---------------------------------------------------------------------------
// h = z @ W   (4 rows per block, W staged in LDS)
__global__ __launch_bounds__(256) void h_kernel(const float* __restrict__ z,
                                                const float* __restrict__ W,
                                                float* __restrict__ h) {
    __shared__ float Ws[64 * 64];
    __shared__ float zs[4 * 64];
    const int tid = threadIdx.x;
    const int rbase = blockIdx.x * 4;
#pragma unroll
    for (int i = 0; i < 16; i++) Ws[i * 256 + tid] = W[i * 256 + tid];
    zs[tid] = z[rbase * DD + tid];
    __syncthreads();
    const int r = tid >> 6, d = tid & 63;
    float acc = 0.0f;
#pragma unroll
    for (int k = 0; k < 64; k++) acc = fmaf(zs[r * 64 + k], Ws[k * 64 + d], acc);
    h[(rbase + r) * DD + d] = acc;
}

// ---------------------------------------------------------------------------
// gather-aggregate: one wave per destination node, lane = feature dim.
// zr = relu(sum_in h[r]*dinv[r]*dinv[c] + h[c]*dinv[c]^2 + b); split to bf16 hi/lo
__global__ __launch_bounds__(256) void agg_kernel(const int* __restrict__ rowptr,
                                                  const int* __restrict__ srcrow,
                                                  const float* __restrict__ dinv,
                                                  const float* __restrict__ h,
                                                  const float* __restrict__ b,
                                                  __bf16* __restrict__ zr1,
                                                  __bf16* __restrict__ zr2) {
    const int lane = threadIdx.x & 63;
    const int n = blockIdx.x * 4 + (threadIdx.x >> 6);
    if (n >= NN) return;
    int s = __builtin_amdgcn_readfirstlane(rowptr[n]);
    int e = __builtin_amdgcn_readfirstlane(rowptr[n + 1]);
    const float dc = dinv[n];
    float acc = 0.0f;
    int i = s;
    // 2-deep manual pipeline to overlap srcrow->h latency
    for (; i + 1 < e; i += 2) {
        int r0 = __builtin_amdgcn_readfirstlane(srcrow[i]);
        int r1 = __builtin_amdgcn_readfirstlane(srcrow[i + 1]);
        float n0 = dinv[r0] * dc, n1 = dinv[r1] * dc;
        float h0 = h[r0 * DD + lane], h1 = h[r1 * DD + lane];
        acc = fmaf(h0, n0, acc);
        acc = fmaf(h1, n1, acc);
    }
    for (; i < e; i++) {
        int r = __builtin_amdgcn_readfirstlane(srcrow[i]);
        acc = fmaf(h[r * DD + lane], dinv[r] * dc, acc);
    }
    acc = fmaf(h[n * DD + lane], dc * dc, acc) + b[lane];
    acc = acc > 0.0f ? acc : 0.0f;
    __bf16 hi = (__bf16)acc;
    float rem = acc - (float)hi;
    zr1[n * DD + lane] = hi;
    zr2[n * DD + lane] = (__bf16)rem;
}

// ---------------------------------------------------------------------------
// C = zr @ zr^T via bf16x3-split MFMA. 128x128/block, 4 waves 2x2, each wave
// 64x64 = 4x4 tiles of 16x16, K=64 in 2 steps of 32 (mfma_f32_16x16x32_bf16).
__global__ __launch_bounds__(256) void gemm_kernel(const __bf16* __restrict__ z1,
                                                   const __bf16* __restrict__ z2,
                                                   float* __restrict__ C) {
    const int tid = threadIdx.x;
    const int lane = tid & 63;
    const int w = tid >> 6;
    const int wr = w >> 1, wc = w & 1;
    const int m16 = lane & 15;
    const int kq = lane >> 4;
    const int rbase = blockIdx.y * TILE + wr * 64;
    const int cbase = blockIdx.x * TILE + wc * 64;

    f32x4 acc[4][4] = {};

    for (int kk = 0; kk < 2; kk++) {
        const int ko = kk * 32 + kq * 8;
        bf16x8 a1[4], a2[4], b1[4], b2[4];
#pragma unroll
        for (int t = 0; t < 4; t++) {
            const int ar = rbase + t * 16 + m16;
            const int br = cbase + t * 16 + m16;
            a1[t] = *(const bf16x8*)&z1[ar * DD + ko];
            a2[t] = *(const bf16x8*)&z2[ar * DD + ko];
            b1[t] = *(const bf16x8*)&z1[br * DD + ko];
            b2[t] = *(const bf16x8*)&z2[br * DD + ko];
        }
#pragma unroll
        for (int mt = 0; mt < 4; mt++)
#pragma unroll
            for (int nt = 0; nt < 4; nt++) {
                acc[mt][nt] = __builtin_amdgcn_mfma_f32_16x16x32_bf16(a2[mt], b1[nt], acc[mt][nt], 0, 0, 0);
                acc[mt][nt] = __builtin_amdgcn_mfma_f32_16x16x32_bf16(a1[mt], b2[nt], acc[mt][nt], 0, 0, 0);
                acc[mt][nt] = __builtin_amdgcn_mfma_f32_16x16x32_bf16(a1[mt], b1[nt], acc[mt][nt], 0, 0, 0);
            }
    }

    // C/D layout (verified): col = lane&15, row = (lane>>4)*4 + reg
#pragma unroll
    for (int mt = 0; mt < 4; mt++) {
        const int row0 = rbase + mt * 16 + kq * 4;
#pragma unroll
        for (int nt = 0; nt < 4; nt++) {
            const int col = cbase + nt * 16 + m16;
            if (col < NN) {
#pragma unroll
                for (int r = 0; r < 4; r++) {
                    const int row = row0 + r;
                    if (row < NN) C[(size_t)row * NN + col] = acc[mt][nt][r];
                }
            }
        }
    }
}

// ---------------------------------------------------------------------------
extern "C" void kernel_launch(void* const* d_in, const int* in_sizes, int n_in,
                              void* d_out, int out_size, void* d_ws, size_t ws_size,
                              hipStream_t stream) {
    const float* z = (const float*)d_in[0];
    const int* ei = (const int*)d_in[1];  // [2, E]: row=ei[0:E], col=ei[E:2E]
    const float* W = (const float*)d_in[2];
    const float* b = (const float*)d_in[3];
    float* C = (float*)d_out;

    char* ws = (char*)d_ws;
    int* cnt = (int*)(ws + OFF_CNT);
    int* fill = (int*)(ws + OFF_FILL);
    int* rowptr = (int*)(ws + OFF_ROWPTR);
    int* srcrow = (int*)(ws + OFF_SRC);
    float* dinv = (float*)(ws + OFF_DINV);
    float* h = (float*)(ws + OFF_H);
    __bf16* zr1 = (__bf16*)(ws + OFF_ZR1);
    __bf16* zr2 = (__bf16*)(ws + OFF_ZR2);

    init_kernel<<<(NN + 255) / 256, 256, 0, stream>>>(cnt, fill,
                                                      (unsigned short*)zr1,
                                                      (unsigned short*)zr2);
    count_kernel<<<(NE + 255) / 256, 256, 0, stream>>>(ei, cnt);
    dinv_kernel<<<(NN + 255) / 256, 256, 0, stream>>>(cnt, dinv);
    scan_kernel<<<1, 256, 0, stream>>>(cnt, rowptr);
    fill_kernel<<<(NE + 255) / 256, 256, 0, stream>>>(ei, rowptr, fill, srcrow);
    h_kernel<<<NN / 4, 256, 0, stream>>>(z, W, h);
    agg_kernel<<<(NN + 3) / 4, 256, 0, stream>>>(rowptr, srcrow, dinv, h, b, zr1, zr2);

    dim3 grid(NTILE, NTILE);
    gemm_kernel<<<grid, 256, 0, stream>>>(zr1, zr2, C);
}